// Round 1
// baseline (119.141 us; speedup 1.0000x reference)
//
#include <hip/hip_runtime.h>

// Problem constants (from reference)
#define Bsz  32
#define Nn   512
#define DIN  256
#define DSC  32
#define Cc   48
#define Hh   152
#define Ww   160
#define HW   (Hh * Ww)        // 24320
#define COUT (Cc + DSC)       // 80

// ---------------------------------------------------------------------------
// Kernel 1: assemble output. Channels [0,48) <- spatial_info, [48,80) <- 0.
// One block per (b, c) plane; float4 grid-stride within the plane.
// ---------------------------------------------------------------------------
__global__ __launch_bounds__(256) void init_out_kernel(
    const float* __restrict__ spatial, float* __restrict__ out) {
    const int plane = blockIdx.x;           // 0 .. B*COUT-1
    const int b = plane / COUT;
    const int c = plane % COUT;
    float4* dst = (float4*)(out + (size_t)plane * HW);
    const int nvec = HW / 4;                // 6080
    if (c < Cc) {
        const float4* src = (const float4*)(spatial + ((size_t)b * Cc + c) * HW);
        for (int i = threadIdx.x; i < nvec; i += blockDim.x) dst[i] = src[i];
    } else {
        const float4 z = make_float4(0.f, 0.f, 0.f, 0.f);
        for (int i = threadIdx.x; i < nvec; i += blockDim.x) dst[i] = z;
    }
}

// ---------------------------------------------------------------------------
// Kernel 2: proj = relu(emb @ W + b) * mask, scatter-add into out[:,48:80,:,:]
// 256 threads/block, 32 entities/block, 8 threads per entity, 4 channels each.
// W (256x32, 32KB) and 32 entity rows staged in LDS.
// Es padded to 260 floats/row so the 8 distinct ds_read_b128 per wave cover
// all 32 banks (stride 1040B -> bank start (4g+k)%32). Ws reads: same address
// across the 4 entity-groups of a wave -> broadcast; 8 lanes x 16B cover all
// 32 banks. Conflict-free.
// ---------------------------------------------------------------------------
__global__ __launch_bounds__(256) void scatter_kernel(
    const float* __restrict__ emb, const float* __restrict__ mask,
    const int* __restrict__ loc, const float* __restrict__ Wp,
    const float* __restrict__ bp, float* __restrict__ out) {

    __shared__ float Ws[DIN][DSC];        // 32 KB, same layout as global
    __shared__ float Es[32][DIN + 4];     // 32.5 KB, +4 pad for bank spread

    const int tid  = threadIdx.x;
    const int ent0 = blockIdx.x * 32;

    // Stage W: 2048 float4 / 256 threads = 8 iters, coalesced.
    for (int i = tid; i < (DIN * DSC) / 4; i += 256)
        ((float4*)Ws)[i] = ((const float4*)Wp)[i];
    // Stage 32 entity rows: 2048 float4, coalesced per row.
    for (int i = tid; i < (32 * DIN) / 4; i += 256) {
        const int e  = i >> 6;            // / 64 float4 per row
        const int k4 = i & 63;
        *(float4*)&Es[e][k4 * 4] =
            ((const float4*)(emb + (size_t)(ent0 + e) * DIN))[k4];
    }
    __syncthreads();

    const int g   = tid >> 3;             // entity within block, 0..31
    const int dq  = (tid & 7) * 4;        // first of 4 output channels
    const int ent = ent0 + g;
    const int b   = ent >> 9;             // / N (=512)

    float ax = bp[dq + 0], ay = bp[dq + 1], az = bp[dq + 2], aw = bp[dq + 3];

    #pragma unroll 4
    for (int k = 0; k < DIN; k += 4) {
        const float4 ev = *(const float4*)&Es[g][k];
        const float4 w0 = *(const float4*)&Ws[k + 0][dq];
        const float4 w1 = *(const float4*)&Ws[k + 1][dq];
        const float4 w2 = *(const float4*)&Ws[k + 2][dq];
        const float4 w3 = *(const float4*)&Ws[k + 3][dq];
        ax = fmaf(ev.x, w0.x, fmaf(ev.y, w1.x, fmaf(ev.z, w2.x, fmaf(ev.w, w3.x, ax))));
        ay = fmaf(ev.x, w0.y, fmaf(ev.y, w1.y, fmaf(ev.z, w2.y, fmaf(ev.w, w3.y, ay))));
        az = fmaf(ev.x, w0.z, fmaf(ev.y, w1.z, fmaf(ev.z, w2.z, fmaf(ev.w, w3.z, az))));
        aw = fmaf(ev.x, w0.w, fmaf(ev.y, w1.w, fmaf(ev.z, w2.w, fmaf(ev.w, w3.w, aw))));
    }

    const float m = mask[ent];
    int y = loc[2 * ent + 0];
    int x = loc[2 * ent + 1];
    y = min(max(y, 0), Hh - 1);
    x = min(max(x, 0), Ww - 1);

    float* dst = out + ((size_t)b * COUT + Cc) * HW + (size_t)y * Ww + x;
    float v[4] = { ax, ay, az, aw };
    #pragma unroll
    for (int j = 0; j < 4; ++j) {
        const float r = fmaxf(v[j], 0.f) * m;
        if (r != 0.f)  // exact: adding 0.0f never changes a finite cell value
            atomicAdd(dst + (size_t)(dq + j) * HW, r);
    }
}

// ---------------------------------------------------------------------------
extern "C" void kernel_launch(void* const* d_in, const int* in_sizes, int n_in,
                              void* d_out, int out_size, void* d_ws, size_t ws_size,
                              hipStream_t stream) {
    const float* spatial = (const float*)d_in[0];  // [B, C, H, W]
    const float* emb     = (const float*)d_in[1];  // [B, N, DIN]
    const float* mask    = (const float*)d_in[2];  // [B, N]
    const int*   loc     = (const int*)d_in[3];    // [B, N, 2]
    const float* Wp      = (const float*)d_in[4];  // [DIN, DSC]
    const float* bp      = (const float*)d_in[5];  // [DSC]
    float* out = (float*)d_out;                    // [B, COUT, H, W]

    init_out_kernel<<<Bsz * COUT, 256, 0, stream>>>(spatial, out);
    scatter_kernel<<<(Bsz * Nn) / 32, 256, 0, stream>>>(emb, mask, loc, Wp, bp, out);
}

// Round 2
// 102.176 us; speedup vs baseline: 1.1660x; 1.1660x over previous
//
#include <hip/hip_runtime.h>

// Problem constants (from reference)
#define Bsz  32
#define Nn   512
#define DIN  256
#define DSC  32
#define Cc   48
#define Hh   152
#define Ww   160
#define HW   (Hh * Ww)        // 24320
#define COUT (Cc + DSC)       // 80
#define TILE 256              // cells per gather block; HW/TILE = 95 exactly
#define TPB  95               // gather tiles per batch

// ---------------------------------------------------------------------------
// K1: proj = relu(emb @ W + b) * mask -> projws [B*N, DSC] (2 MB, L2-resident)
//     also flat cell index per entity -> idxws [B*N]
// 256 threads/block, 32 entities/block, 8 threads x 4 channels per entity.
// ---------------------------------------------------------------------------
__global__ __launch_bounds__(256) void proj_kernel(
    const float* __restrict__ emb, const float* __restrict__ mask,
    const int* __restrict__ loc, const float* __restrict__ Wp,
    const float* __restrict__ bp, float* __restrict__ projws,
    int* __restrict__ idxws) {

    __shared__ float Ws[DIN][DSC];        // 32 KB
    __shared__ float Es[32][DIN + 4];     // 32.5 KB, +4 pad for bank spread

    const int tid  = threadIdx.x;
    const int ent0 = blockIdx.x * 32;

    for (int i = tid; i < (DIN * DSC) / 4; i += 256)
        ((float4*)Ws)[i] = ((const float4*)Wp)[i];
    for (int i = tid; i < (32 * DIN) / 4; i += 256) {
        const int e  = i >> 6;
        const int k4 = i & 63;
        *(float4*)&Es[e][k4 * 4] =
            ((const float4*)(emb + (size_t)(ent0 + e) * DIN))[k4];
    }
    __syncthreads();

    const int g   = tid >> 3;             // entity within block
    const int dq  = (tid & 7) * 4;        // first of 4 output channels
    const int ent = ent0 + g;

    float ax = bp[dq + 0], ay = bp[dq + 1], az = bp[dq + 2], aw = bp[dq + 3];

    #pragma unroll 4
    for (int k = 0; k < DIN; k += 4) {
        const float4 ev = *(const float4*)&Es[g][k];
        const float4 w0 = *(const float4*)&Ws[k + 0][dq];
        const float4 w1 = *(const float4*)&Ws[k + 1][dq];
        const float4 w2 = *(const float4*)&Ws[k + 2][dq];
        const float4 w3 = *(const float4*)&Ws[k + 3][dq];
        ax = fmaf(ev.x, w0.x, fmaf(ev.y, w1.x, fmaf(ev.z, w2.x, fmaf(ev.w, w3.x, ax))));
        ay = fmaf(ev.x, w0.y, fmaf(ev.y, w1.y, fmaf(ev.z, w2.y, fmaf(ev.w, w3.y, ay))));
        az = fmaf(ev.x, w0.z, fmaf(ev.y, w1.z, fmaf(ev.z, w2.z, fmaf(ev.w, w3.z, az))));
        aw = fmaf(ev.x, w0.w, fmaf(ev.y, w1.w, fmaf(ev.z, w2.w, fmaf(ev.w, w3.w, aw))));
    }

    const float m = mask[ent];
    float4 r;
    r.x = fmaxf(ax, 0.f) * m;
    r.y = fmaxf(ay, 0.f) * m;
    r.z = fmaxf(az, 0.f) * m;
    r.w = fmaxf(aw, 0.f) * m;
    ((float4*)projws)[(size_t)ent * (DSC / 4) + (tid & 7)] = r;

    if ((tid & 7) == 0) {
        int y = loc[2 * ent + 0];
        int x = loc[2 * ent + 1];
        y = min(max(y, 0), Hh - 1);
        x = min(max(x, 0), Ww - 1);
        idxws[ent] = y * Ww + x;
    }
}

// ---------------------------------------------------------------------------
// K2: fused output assembly.
//  blocks [0, B*Cc):       copy spatial plane (b,c) -> out[b][c]
//  blocks [B*Cc, +B*TPB):  gather one (b, 256-cell tile) x 32 channels:
//    zero 32KB LDS acc, scan 512 entity indices (2/thread), LDS-atomicAdd the
//    rare matches, stream acc -> out[b][48..80][tile] as full float4 lines.
// LDS 34.25 KB -> 4 blocks/CU. No global atomics, no separate zero pass.
// ---------------------------------------------------------------------------
__global__ __launch_bounds__(256) void fused_out_kernel(
    const float* __restrict__ spatial, const float* __restrict__ projws,
    const int* __restrict__ idxws, float* __restrict__ out) {

    __shared__ float acc[DSC * TILE];     // 32 KB
    __shared__ int   sidx[Nn];            // 2 KB

    const int bid = blockIdx.x;
    const int tid = threadIdx.x;

    if (bid < Bsz * Cc) {
        const int b = bid / Cc;
        const int c = bid % Cc;
        const float4* src = (const float4*)(spatial + ((size_t)b * Cc + c) * HW);
        float4*       dst = (float4*)(out + ((size_t)b * COUT + c) * HW);
        for (int i = tid; i < HW / 4; i += 256) dst[i] = src[i];
        return;
    }

    const int g  = bid - Bsz * Cc;
    const int b  = g / TPB;
    const int t0 = (g % TPB) * TILE;

    for (int i = tid; i < Nn; i += 256) sidx[i] = idxws[b * Nn + i];
    const float4 z = make_float4(0.f, 0.f, 0.f, 0.f);
    for (int i = tid; i < (DSC * TILE) / 4; i += 256) ((float4*)acc)[i] = z;
    __syncthreads();

    for (int i = tid; i < Nn; i += 256) {
        const int r = sidx[i] - t0;
        if ((unsigned)r < (unsigned)TILE) {
            const float4* p = (const float4*)(projws + ((size_t)b * Nn + i) * DSC);
            #pragma unroll
            for (int j = 0; j < DSC / 4; ++j) {
                const float4 v = p[j];
                atomicAdd(&acc[(4 * j + 0) * TILE + r], v.x);
                atomicAdd(&acc[(4 * j + 1) * TILE + r], v.y);
                atomicAdd(&acc[(4 * j + 2) * TILE + r], v.z);
                atomicAdd(&acc[(4 * j + 3) * TILE + r], v.w);
            }
        }
    }
    __syncthreads();

    for (int v = tid; v < (DSC * TILE) / 4; v += 256) {
        const int c  = v >> 6;            // / (TILE/4)
        const int r4 = (v & 63) * 4;
        *(float4*)(out + ((size_t)b * COUT + Cc + c) * HW + t0 + r4) =
            *(const float4*)&acc[c * TILE + r4];
    }
}

// ---------------------------------------------------------------------------
// Fallback path (used only if ws_size is too small): R1 design.
// ---------------------------------------------------------------------------
__global__ __launch_bounds__(256) void init_out_kernel(
    const float* __restrict__ spatial, float* __restrict__ out) {
    const int plane = blockIdx.x;
    const int b = plane / COUT;
    const int c = plane % COUT;
    float4* dst = (float4*)(out + (size_t)plane * HW);
    if (c < Cc) {
        const float4* src = (const float4*)(spatial + ((size_t)b * Cc + c) * HW);
        for (int i = threadIdx.x; i < HW / 4; i += blockDim.x) dst[i] = src[i];
    } else {
        const float4 z = make_float4(0.f, 0.f, 0.f, 0.f);
        for (int i = threadIdx.x; i < HW / 4; i += blockDim.x) dst[i] = z;
    }
}

__global__ __launch_bounds__(256) void scatter_kernel(
    const float* __restrict__ emb, const float* __restrict__ mask,
    const int* __restrict__ loc, const float* __restrict__ Wp,
    const float* __restrict__ bp, float* __restrict__ out) {

    __shared__ float Ws[DIN][DSC];
    __shared__ float Es[32][DIN + 4];

    const int tid  = threadIdx.x;
    const int ent0 = blockIdx.x * 32;

    for (int i = tid; i < (DIN * DSC) / 4; i += 256)
        ((float4*)Ws)[i] = ((const float4*)Wp)[i];
    for (int i = tid; i < (32 * DIN) / 4; i += 256) {
        const int e  = i >> 6;
        const int k4 = i & 63;
        *(float4*)&Es[e][k4 * 4] =
            ((const float4*)(emb + (size_t)(ent0 + e) * DIN))[k4];
    }
    __syncthreads();

    const int g   = tid >> 3;
    const int dq  = (tid & 7) * 4;
    const int ent = ent0 + g;
    const int b   = ent >> 9;

    float ax = bp[dq + 0], ay = bp[dq + 1], az = bp[dq + 2], aw = bp[dq + 3];

    #pragma unroll 4
    for (int k = 0; k < DIN; k += 4) {
        const float4 ev = *(const float4*)&Es[g][k];
        const float4 w0 = *(const float4*)&Ws[k + 0][dq];
        const float4 w1 = *(const float4*)&Ws[k + 1][dq];
        const float4 w2 = *(const float4*)&Ws[k + 2][dq];
        const float4 w3 = *(const float4*)&Ws[k + 3][dq];
        ax = fmaf(ev.x, w0.x, fmaf(ev.y, w1.x, fmaf(ev.z, w2.x, fmaf(ev.w, w3.x, ax))));
        ay = fmaf(ev.x, w0.y, fmaf(ev.y, w1.y, fmaf(ev.z, w2.y, fmaf(ev.w, w3.y, ay))));
        az = fmaf(ev.x, w0.z, fmaf(ev.y, w1.z, fmaf(ev.z, w2.z, fmaf(ev.w, w3.z, az))));
        aw = fmaf(ev.x, w0.w, fmaf(ev.y, w1.w, fmaf(ev.z, w2.w, fmaf(ev.w, w3.w, aw))));
    }

    const float m = mask[ent];
    int y = loc[2 * ent + 0];
    int x = loc[2 * ent + 1];
    y = min(max(y, 0), Hh - 1);
    x = min(max(x, 0), Ww - 1);

    float* dst = out + ((size_t)b * COUT + Cc) * HW + (size_t)y * Ww + x;
    float v[4] = { ax, ay, az, aw };
    #pragma unroll
    for (int j = 0; j < 4; ++j) {
        const float r = fmaxf(v[j], 0.f) * m;
        if (r != 0.f)
            atomicAdd(dst + (size_t)(dq + j) * HW, r);
    }
}

// ---------------------------------------------------------------------------
extern "C" void kernel_launch(void* const* d_in, const int* in_sizes, int n_in,
                              void* d_out, int out_size, void* d_ws, size_t ws_size,
                              hipStream_t stream) {
    const float* spatial = (const float*)d_in[0];  // [B, C, H, W]
    const float* emb     = (const float*)d_in[1];  // [B, N, DIN]
    const float* mask    = (const float*)d_in[2];  // [B, N]
    const int*   loc     = (const int*)d_in[3];    // [B, N, 2]
    const float* Wp      = (const float*)d_in[4];  // [DIN, DSC]
    const float* bp      = (const float*)d_in[5];  // [DSC]
    float* out = (float*)d_out;                    // [B, COUT, H, W]

    const size_t need = (size_t)Bsz * Nn * DSC * sizeof(float)
                      + (size_t)Bsz * Nn * sizeof(int);
    if (ws_size >= need) {
        float* projws = (float*)d_ws;
        int*   idxws  = (int*)((char*)d_ws + (size_t)Bsz * Nn * DSC * sizeof(float));
        proj_kernel<<<(Bsz * Nn) / 32, 256, 0, stream>>>(emb, mask, loc, Wp, bp,
                                                         projws, idxws);
        fused_out_kernel<<<Bsz * Cc + Bsz * TPB, 256, 0, stream>>>(spatial, projws,
                                                                   idxws, out);
    } else {
        init_out_kernel<<<Bsz * COUT, 256, 0, stream>>>(spatial, out);
        scatter_kernel<<<(Bsz * Nn) / 32, 256, 0, stream>>>(emb, mask, loc, Wp, bp, out);
    }
}